// Round 5
// baseline (2034.151 us; speedup 1.0000x reference)
//
#include <hip/hip_runtime.h>

#define BATCH 2
#define SEQ 1024
#define DM 1024
#define DI 2048
#define DSTATE 16
#define NP (DI + 2*DSTATE)   /* 2080 */
#define ROWS (BATCH*SEQ)     /* 2048 */
#define NCH 16               /* scan chunks */
#define CHT (SEQ/NCH)        /* 64 timesteps per chunk */
#define CSZ (BATCH*DI*DSTATE) /* 65536 recurrences */

__device__ __forceinline__ float softplus_f(float x){
  return fmaxf(x, 0.0f) + log1pf(expf(-fabsf(x)));
}

// ---------------------------------------------------------------------------
// Tiled f32 GEMM, 128x128 tile, BK=16, 256 thr, 8x8/thread.
// Double-buffered LDS (1 barrier/tile) + register prefetch of next tile.
// Split-K via blockIdx.z over kseg-sized K segments.
// EPI=0: C = acc + bias (direct float4 store; full-sum launch only, gz==1)
// EPI=1: atomicAdd(C, acc + (kid==0 ? bias : 0))  -- C must be pre-zeroed
// ---------------------------------------------------------------------------
template<int EPI>
__global__ __launch_bounds__(256, 2) void gemm_f32_kernel(
    const float* __restrict__ A, int lda,
    const float* __restrict__ B, int ldb,
    const float* __restrict__ bias,
    float* __restrict__ C, int ldc,
    int N, int kseg)
{
  constexpr int BM = 128, BN = 128, BK = 16;
  __shared__ float As[2][BK][BM + 4];
  __shared__ float Bs[2][BK][BN + 4];

  const int t   = threadIdx.x;
  const int bm  = blockIdx.y * BM;
  const int bn  = blockIdx.x * BN;
  const int kid = blockIdx.z;
  const int kbase = kid * kseg;
  const int tm  = (t >> 4) << 3;
  const int tn  = (t & 15) << 3;

  float4 va[2], vb[2];

  auto LOAD = [&](int k0) {
    #pragma unroll
    for (int j = 0; j < 2; ++j) {
      int f  = t + 256 * j;
      int m  = f >> 2;
      int k4 = (f & 3) << 2;
      va[j] = *reinterpret_cast<const float4*>(A + (size_t)(bm + m) * lda + (k0 + k4));
      int kk = f >> 5;
      int n4 = (f & 31) << 2;
      int ncol = bn + n4;
      if (ncol < N)
        vb[j] = *reinterpret_cast<const float4*>(B + (size_t)(k0 + kk) * ldb + ncol);
      else
        vb[j] = make_float4(0.f, 0.f, 0.f, 0.f);
    }
  };
  auto STORE = [&](int s) {
    #pragma unroll
    for (int j = 0; j < 2; ++j) {
      int f  = t + 256 * j;
      int m  = f >> 2;
      int k4 = (f & 3) << 2;
      As[s][k4 + 0][m] = va[j].x;
      As[s][k4 + 1][m] = va[j].y;
      As[s][k4 + 2][m] = va[j].z;
      As[s][k4 + 3][m] = va[j].w;
      int kk = f >> 5;
      int n4 = (f & 31) << 2;
      *reinterpret_cast<float4*>(&Bs[s][kk][n4]) = vb[j];
    }
  };

  float acc[8][8];
  #pragma unroll
  for (int i = 0; i < 8; ++i)
    #pragma unroll
    for (int j = 0; j < 8; ++j) acc[i][j] = 0.0f;

  auto COMPUTE = [&](int s) {
    #pragma unroll
    for (int kk = 0; kk < BK; ++kk) {
      float a[8], b[8];
      *reinterpret_cast<float4*>(&a[0]) = *reinterpret_cast<const float4*>(&As[s][kk][tm]);
      *reinterpret_cast<float4*>(&a[4]) = *reinterpret_cast<const float4*>(&As[s][kk][tm + 4]);
      *reinterpret_cast<float4*>(&b[0]) = *reinterpret_cast<const float4*>(&Bs[s][kk][tn]);
      *reinterpret_cast<float4*>(&b[4]) = *reinterpret_cast<const float4*>(&Bs[s][kk][tn + 4]);
      #pragma unroll
      for (int i = 0; i < 8; ++i)
        #pragma unroll
        for (int j = 0; j < 8; ++j)
          acc[i][j] = fmaf(a[i], b[j], acc[i][j]);
    }
  };

  LOAD(kbase);
  STORE(0);
  __syncthreads();

  const int NT = kseg >> 4;
  for (int it = 0; it < NT; ++it) {
    if (it + 1 < NT) {
      LOAD(kbase + ((it + 1) << 4));   // global -> regs (vmcnt waits at STORE)
      COMPUTE(it & 1);
      STORE((it + 1) & 1);
      __syncthreads();
    } else {
      COMPUTE(it & 1);
    }
  }

  if (EPI == 0) {
    #pragma unroll
    for (int i = 0; i < 8; ++i) {
      float* crow = C + (size_t)(bm + tm + i) * ldc;
      #pragma unroll
      for (int j0 = 0; j0 < 8; j0 += 4) {
        int c = bn + tn + j0;
        if (c < N) {
          float4 bv = *reinterpret_cast<const float4*>(bias + c);
          float4 v  = make_float4(acc[i][j0 + 0] + bv.x, acc[i][j0 + 1] + bv.y,
                                  acc[i][j0 + 2] + bv.z, acc[i][j0 + 3] + bv.w);
          *reinterpret_cast<float4*>(crow + c) = v;
        }
      }
    }
  } else {
    const bool addb = (kid == 0);
    #pragma unroll
    for (int i = 0; i < 8; ++i) {
      float* crow = C + (size_t)(bm + tm + i) * ldc;
      #pragma unroll
      for (int j = 0; j < 8; ++j) {
        int c = bn + tn + j;
        if (c < N) atomicAdd(crow + c, acc[i][j] + (addb ? bias[c] : 0.0f));
      }
    }
  }
}

// ---------------------------------------------------------------------------
// Causal depthwise conv (D_CONV=4) + heaviside spike.
// ---------------------------------------------------------------------------
__global__ __launch_bounds__(256) void conv_spike_kernel(
    const float* __restrict__ xr, const float* __restrict__ W_conv,
    const float* __restrict__ b_conv, float* __restrict__ spikes)
{
  int g   = blockIdx.x * 256 + threadIdx.x;
  int c   = g & (DI - 1);
  int row = g >> 11;
  int t   = row & (SEQ - 1);

  float4 wc = reinterpret_cast<const float4*>(W_conv)[c];
  float w[4] = { wc.x, wc.y, wc.z, wc.w };
  float v = b_conv[c];
  #pragma unroll
  for (int k = 0; k < 4; ++k) {
    int tt = t - 3 + k;
    if (tt >= 0) {
      float xv = xr[(size_t)(row - 3 + k) * (2 * DI) + c];
      v = fmaf(xv, w[k], v);
    }
  }
  spikes[(size_t)row * DI + c] = (v >= 1.0f) ? 1.0f : 0.0f;
}

// ---------------------------------------------------------------------------
// Chunked selective scan. delta buffer holds PRE-softplus values (G3 raw sum
// including bias); softplus applied here.
// g bits: (c, b, d, s) = (g>>16, (g>>15)&1, (g>>4)&2047, g&15).
// ---------------------------------------------------------------------------
__global__ __launch_bounds__(256) void scan_pass1(
    const float* __restrict__ delta, const float* __restrict__ spikes,
    const float* __restrict__ bc, const float* __restrict__ A_log,
    float* __restrict__ hpart, float* __restrict__ Ppart)
{
  int g = blockIdx.x * 256 + threadIdx.x;
  int s = g & 15;
  int d = (g >> 4) & (DI - 1);
  int b = (g >> 15) & (BATCH - 1);
  int c = g >> 16;

  float A_s = -expf(A_log[(size_t)d * DSTATE + s]);
  size_t row0 = (size_t)b * SEQ + c * CHT;
  const float* pD = delta  + row0 * DI + d;
  const float* pS = spikes + row0 * DI + d;
  const float* pB = bc     + row0 * NP + s;

  float h = 0.0f, P = 1.0f;
  for (int t = 0; t < CHT; ++t) {
    float dl = softplus_f(*pD);
    float sp = *pS, Bp = *pB;
    float a = expf(dl * A_s);
    h = fmaf(a, h, (dl * sp) * Bp);
    P *= a;
    pD += DI; pS += DI; pB += NP;
  }
  hpart[g] = h;
  Ppart[g] = P;
}

__global__ __launch_bounds__(256) void scan_combine(
    const float* __restrict__ hpart, const float* __restrict__ Ppart,
    float* __restrict__ init)
{
  int q = blockIdx.x * 256 + threadIdx.x;   // [0, CSZ)
  float H = 0.0f;
  #pragma unroll
  for (int c = 0; c < NCH; ++c) {
    init[c * CSZ + q] = H;
    H = fmaf(Ppart[c * CSZ + q], H, hpart[c * CSZ + q]);
  }
}

__global__ __launch_bounds__(256) void scan_pass2(
    const float* __restrict__ delta, const float* __restrict__ spikes,
    const float* __restrict__ bc, const float* __restrict__ xr,
    const float* __restrict__ A_log, const float* __restrict__ D_param,
    const float* __restrict__ init, float* __restrict__ yout)
{
  int g = blockIdx.x * 256 + threadIdx.x;
  int s = g & 15;
  int d = (g >> 4) & (DI - 1);
  int b = (g >> 15) & (BATCH - 1);
  int c = g >> 16;

  float A_s = -expf(A_log[(size_t)d * DSTATE + s]);
  float Dp  = D_param[d];
  size_t row0 = (size_t)b * SEQ + c * CHT;
  const float* pD = delta  + row0 * DI + d;
  const float* pS = spikes + row0 * DI + d;
  const float* pB = bc     + row0 * NP + s;
  const float* pC = pB + DSTATE;
  const float* pR = xr     + row0 * (2 * DI) + DI + d;
  float*       pY = yout   + row0 * NP + d;

  float h = init[g];
  for (int t = 0; t < CHT; ++t) {
    float dl = softplus_f(*pD);
    float sp = *pS, Bp = *pB, Cp = *pC;
    float a = expf(dl * A_s);
    h = fmaf(a, h, (dl * sp) * Bp);
    float v = h * Cp;
    v += __shfl_xor(v, 1, 16);
    v += __shfl_xor(v, 2, 16);
    v += __shfl_xor(v, 4, 16);
    v += __shfl_xor(v, 8, 16);
    if (s == 0) {
      float r   = *pR;
      float sig = 1.0f / (1.0f + expf(-r));
      *pY = (v + sp * Dp) * (r * sig);
    }
    pD += DI; pS += DI; pB += NP; pC += NP; pR += 2 * DI; pY += NP;
  }
}

// ---------------------------------------------------------------------------
// Row LayerNorm + final spike. o holds y@W_out partial sums (+ b_out from
// GEMM kid0); this kernel adds residual x, then normalizes.
// ---------------------------------------------------------------------------
__global__ __launch_bounds__(256) void ln_spike_kernel(
    const float* __restrict__ o, const float* __restrict__ x,
    const float* __restrict__ gamma, const float* __restrict__ beta,
    float* __restrict__ out)
{
  const int row = blockIdx.x;
  const int tid = threadIdx.x;
  const float* orow = o + (size_t)row * DM;
  const float* xrow = x + (size_t)row * DM;

  float vals[4];
  float sum = 0.0f;
  #pragma unroll
  for (int j = 0; j < 4; ++j) {
    int c = tid + 256 * j;
    vals[j] = orow[c] + xrow[c];
    sum += vals[j];
  }
  #pragma unroll
  for (int off = 1; off < 64; off <<= 1) sum += __shfl_xor(sum, off, 64);

  __shared__ float ws4[4];
  const int wid = tid >> 6, lane = tid & 63;
  if (lane == 0) ws4[wid] = sum;
  __syncthreads();
  float mu = (ws4[0] + ws4[1] + ws4[2] + ws4[3]) * (1.0f / DM);

  float vs = 0.0f;
  #pragma unroll
  for (int j = 0; j < 4; ++j) { float dv = vals[j] - mu; vs += dv * dv; }
  #pragma unroll
  for (int off = 1; off < 64; off <<= 1) vs += __shfl_xor(vs, off, 64);
  __syncthreads();
  if (lane == 0) ws4[wid] = vs;
  __syncthreads();
  float var = (ws4[0] + ws4[1] + ws4[2] + ws4[3]) * (1.0f / DM);
  float inv = 1.0f / sqrtf(var + 1e-5f);

  float* outrow = out + (size_t)row * DM;
  #pragma unroll
  for (int j = 0; j < 4; ++j) {
    int c = tid + 256 * j;
    float nv = fmaf((vals[j] - mu) * inv, gamma[c], beta[c]);
    outrow[c] = (nv >= 1.0f) ? 1.0f : 0.0f;
  }
}

// ---------------------------------------------------------------------------
extern "C" void kernel_launch(void* const* d_in, const int* in_sizes, int n_in,
                              void* d_out, int out_size, void* d_ws, size_t ws_size,
                              hipStream_t stream) {
  const float* x      = (const float*)d_in[0];
  const float* W_in   = (const float*)d_in[1];
  const float* b_in   = (const float*)d_in[2];
  const float* W_conv = (const float*)d_in[3];
  const float* b_conv = (const float*)d_in[4];
  const float* W_x    = (const float*)d_in[5];
  const float* b_x    = (const float*)d_in[6];
  const float* W_dt   = (const float*)d_in[7];
  const float* b_dt   = (const float*)d_in[8];
  const float* A_log  = (const float*)d_in[9];
  const float* D_par  = (const float*)d_in[10];
  const float* W_out  = (const float*)d_in[11];
  const float* b_out  = (const float*)d_in[12];
  const float* gamma  = (const float*)d_in[13];
  const float* beta   = (const float*)d_in[14];
  float* out = (float*)d_out;

  // workspace layout (floats)
  float* ws     = (float*)d_ws;
  float* xr     = ws;                                  // [ROWS, 2*DI]
  float* spikes = xr     + (size_t)ROWS * (2 * DI);    // [ROWS, DI]
  float* params = spikes + (size_t)ROWS * DI;          // [ROWS, NP]
  float* delta  = params + (size_t)ROWS * NP;          // [ROWS, DI] (pre-softplus)
  float* hpart  = delta  + (size_t)ROWS * DI;          // [NCH*CSZ]
  float* Ppart  = hpart  + (size_t)NCH * CSZ;          // [NCH*CSZ]
  float* init   = Ppart  + (size_t)NCH * CSZ;          // [NCH*CSZ]
  float* o      = spikes;  // spikes dead after scan_pass2

  dim3 blk(256);

  // zero split-K accumulation targets (ordered on stream)
  hipMemsetAsync(params, 0, (size_t)ROWS * NP * sizeof(float), stream);
  hipMemsetAsync(delta,  0, (size_t)ROWS * DI * sizeof(float), stream);

  // G1: xr = x @ W_in + b_in          [2048 x 4096, K=1024], 512 blocks
  gemm_f32_kernel<0><<<dim3(32, 16, 1), blk, 0, stream>>>(
      x, DM, W_in, 2 * DI, b_in, xr, 2 * DI, 2 * DI, DM);

  // conv + spike
  conv_spike_kernel<<<(ROWS * DI) / 256, blk, 0, stream>>>(xr, W_conv, b_conv, spikes);

  // G2: params += spikes @ W_x (+b_x) [2048 x 2080, K=2x1024], 544 blocks
  gemm_f32_kernel<1><<<dim3(17, 16, 2), blk, 0, stream>>>(
      spikes, DI, W_x, NP, b_x, params, NP, NP, 1024);

  // G3: delta += delta_pre @ W_dt (+b_dt)  [2048 x 2048, K=2x1024], 512 blocks
  gemm_f32_kernel<1><<<dim3(16, 16, 2), blk, 0, stream>>>(
      params, NP, W_dt, DI, b_dt, delta, DI, DI, 1024);

  // chunked selective scan (softplus fused on delta reads)
  scan_pass1<<<(NCH * CSZ) / 256, blk, 0, stream>>>(
      delta, spikes, params + DI, A_log, hpart, Ppart);
  scan_combine<<<CSZ / 256, blk, 0, stream>>>(hpart, Ppart, init);
  scan_pass2<<<(NCH * CSZ) / 256, blk, 0, stream>>>(
      delta, spikes, params + DI, xr, A_log, D_par, init, params);

  // G4: o += y @ W_out (+b_out)       [2048 x 1024, K=4x512], 512 blocks
  hipMemsetAsync(o, 0, (size_t)ROWS * DM * sizeof(float), stream);  // after pass2 (o aliases spikes)
  gemm_f32_kernel<1><<<dim3(8, 16, 4), blk, 0, stream>>>(
      params, NP, W_out, DM, b_out, o, DM, DM, 512);

  // LayerNorm(+x residual) + spike -> out
  ln_spike_kernel<<<ROWS, blk, 0, stream>>>(o, x, gamma, beta, out);
}

// Round 6
// 1583.448 us; speedup vs baseline: 1.2846x; 1.2846x over previous
//
#include <hip/hip_runtime.h>

#define BATCH 2
#define SEQ 1024
#define DM 1024
#define DI 2048
#define DSTATE 16
#define NP (DI + 2*DSTATE)   /* 2080 */
#define ROWS (BATCH*SEQ)     /* 2048 */
#define NCH 16               /* scan chunks */
#define CHT (SEQ/NCH)        /* 64 timesteps per chunk */
#define CSZ (BATCH*DI*DSTATE) /* 65536 recurrences */

__device__ __forceinline__ float softplus_f(float x){
  return fmaxf(x, 0.0f) + log1pf(expf(-fabsf(x)));
}

// ---------------------------------------------------------------------------
// Tiled f32 GEMM, 128x128 tile, 512 threads = 2 wave-groups of 256.
// Wave-group wg handles K-half [kbase + wg*kseg/2, +kseg/2) with its own
// double-buffered LDS stage (1 barrier/tile); partials merged through LDS at
// the end (no atomics, no extra global buffers). 8x8 acc per thread.
// Optional inter-block split-K via blockIdx.z writing to C + kid*pstride
// (bias only added by kid 0). ACT: 0 = none, 1 = softplus.
// ---------------------------------------------------------------------------
template<int ACT>
__global__ __launch_bounds__(512, 1) void gemm_f32_kernel(
    const float* __restrict__ A, int lda,
    const float* __restrict__ B, int ldb,
    const float* __restrict__ bias,
    float* __restrict__ C, int ldc,
    int N, int kseg, long long pstride)
{
  // smem carving (floats):
  //  stage: As[db][wg][16][132] = 8448 | Bs same at +8448  (16896 total)
  //  reduce (after compute): 256 slots * 68 floats = 17408
  __shared__ float4 smem4[4352];   // 69632 B
  float* smem = (float*)smem4;
  float* AsB  = smem;
  float* BsB  = smem + 8448;

  const int t   = threadIdx.x;
  const int wg  = t >> 8;          // K-half group
  const int tt  = t & 255;
  const int bm  = blockIdx.y * 128;
  const int bn  = blockIdx.x * 128;
  const int kid = blockIdx.z;
  const int tm  = (tt >> 4) << 3;
  const int tn  = (tt & 15) << 3;

  C += (long long)kid * pstride;
  const int kbase = kid * kseg + wg * (kseg >> 1);
  const int NT    = kseg >> 5;     // tiles of 16 per wave-group

  float4 va[2], vb[2];

  auto LOAD = [&](int k0) {
    #pragma unroll
    for (int j = 0; j < 2; ++j) {
      int f  = tt + 256 * j;
      int m  = f >> 2;
      int k4 = (f & 3) << 2;
      va[j] = *reinterpret_cast<const float4*>(A + (size_t)(bm + m) * lda + (k0 + k4));
      int kk = f >> 5;
      int n4 = (f & 31) << 2;
      int ncol = bn + n4;
      if (ncol < N)
        vb[j] = *reinterpret_cast<const float4*>(B + (size_t)(k0 + kk) * ldb + ncol);
      else
        vb[j] = make_float4(0.f, 0.f, 0.f, 0.f);
    }
  };
  auto STORE = [&](int s) {
    float* as = AsB + ((s * 2 + wg) * 16) * 132;
    float* bs = BsB + ((s * 2 + wg) * 16) * 132;
    #pragma unroll
    for (int j = 0; j < 2; ++j) {
      int f  = tt + 256 * j;
      int m  = f >> 2;
      int k4 = (f & 3) << 2;
      as[(k4 + 0) * 132 + m] = va[j].x;
      as[(k4 + 1) * 132 + m] = va[j].y;
      as[(k4 + 2) * 132 + m] = va[j].z;
      as[(k4 + 3) * 132 + m] = va[j].w;
      int kk = f >> 5;
      int n4 = (f & 31) << 2;
      *reinterpret_cast<float4*>(&bs[kk * 132 + n4]) = vb[j];
    }
  };

  float acc[8][8];
  #pragma unroll
  for (int i = 0; i < 8; ++i)
    #pragma unroll
    for (int j = 0; j < 8; ++j) acc[i][j] = 0.0f;

  auto COMPUTE = [&](int s) {
    const float* as = AsB + ((s * 2 + wg) * 16) * 132;
    const float* bs = BsB + ((s * 2 + wg) * 16) * 132;
    #pragma unroll
    for (int kk = 0; kk < 16; ++kk) {
      float a[8], b[8];
      *reinterpret_cast<float4*>(&a[0]) = *reinterpret_cast<const float4*>(&as[kk * 132 + tm]);
      *reinterpret_cast<float4*>(&a[4]) = *reinterpret_cast<const float4*>(&as[kk * 132 + tm + 4]);
      *reinterpret_cast<float4*>(&b[0]) = *reinterpret_cast<const float4*>(&bs[kk * 132 + tn]);
      *reinterpret_cast<float4*>(&b[4]) = *reinterpret_cast<const float4*>(&bs[kk * 132 + tn + 4]);
      #pragma unroll
      for (int i = 0; i < 8; ++i)
        #pragma unroll
        for (int j = 0; j < 8; ++j)
          acc[i][j] = fmaf(a[i], b[j], acc[i][j]);
    }
  };

  LOAD(kbase);
  STORE(0);
  __syncthreads();

  for (int it = 0; it < NT; ++it) {
    if (it + 1 < NT) {
      LOAD(kbase + ((it + 1) << 4));   // prefetch next tile into regs
      COMPUTE(it & 1);
      STORE((it + 1) & 1);
      __syncthreads();
    } else {
      COMPUTE(it & 1);
    }
  }

  // ---- merge the two K-half partials through LDS, then epilogue ----
  __syncthreads();                     // all compute done; smem reusable
  float* slot = smem + tt * 68;        // 68-stride: 16B-aligned, mild conflicts
  if (wg == 1) {
    #pragma unroll
    for (int i = 0; i < 8; ++i)
      #pragma unroll
      for (int j0 = 0; j0 < 8; j0 += 4)
        *reinterpret_cast<float4*>(slot + i * 8 + j0) =
            make_float4(acc[i][j0], acc[i][j0+1], acc[i][j0+2], acc[i][j0+3]);
  }
  __syncthreads();
  if (wg == 0) {
    const bool addb = (kid == 0);
    #pragma unroll
    for (int i = 0; i < 8; ++i) {
      #pragma unroll
      for (int j0 = 0; j0 < 8; j0 += 4) {
        float4 r = *reinterpret_cast<const float4*>(slot + i * 8 + j0);
        acc[i][j0+0] += r.x; acc[i][j0+1] += r.y;
        acc[i][j0+2] += r.z; acc[i][j0+3] += r.w;
      }
      float* crow = C + (size_t)(bm + tm + i) * ldc;
      #pragma unroll
      for (int j0 = 0; j0 < 8; j0 += 4) {
        int c = bn + tn + j0;
        if (c < N) {
          float4 v = make_float4(acc[i][j0], acc[i][j0+1], acc[i][j0+2], acc[i][j0+3]);
          if (addb) {
            float4 bv = *reinterpret_cast<const float4*>(bias + c);
            v.x += bv.x; v.y += bv.y; v.z += bv.z; v.w += bv.w;
          }
          if (ACT == 1) {
            v.x = softplus_f(v.x); v.y = softplus_f(v.y);
            v.z = softplus_f(v.z); v.w = softplus_f(v.w);
          }
          *reinterpret_cast<float4*>(crow + c) = v;
        }
      }
    }
  }
}

// ---------------------------------------------------------------------------
// Causal depthwise conv (D_CONV=4) + heaviside spike.
// ---------------------------------------------------------------------------
__global__ __launch_bounds__(256) void conv_spike_kernel(
    const float* __restrict__ xr, const float* __restrict__ W_conv,
    const float* __restrict__ b_conv, float* __restrict__ spikes)
{
  int g   = blockIdx.x * 256 + threadIdx.x;
  int c   = g & (DI - 1);
  int row = g >> 11;
  int t   = row & (SEQ - 1);

  float4 wc = reinterpret_cast<const float4*>(W_conv)[c];
  float w[4] = { wc.x, wc.y, wc.z, wc.w };
  float v = b_conv[c];
  #pragma unroll
  for (int k = 0; k < 4; ++k) {
    int tt = t - 3 + k;
    if (tt >= 0) {
      float xv = xr[(size_t)(row - 3 + k) * (2 * DI) + c];
      v = fmaf(xv, w[k], v);
    }
  }
  spikes[(size_t)row * DI + c] = (v >= 1.0f) ? 1.0f : 0.0f;
}

// ---------------------------------------------------------------------------
// Chunked selective scan (delta already softplus'd by G3 epilogue).
// g bits: (c, b, d, s) = (g>>16, (g>>15)&1, (g>>4)&2047, g&15).
// ---------------------------------------------------------------------------
__global__ __launch_bounds__(256) void scan_pass1(
    const float* __restrict__ delta, const float* __restrict__ spikes,
    const float* __restrict__ bc, const float* __restrict__ A_log,
    float* __restrict__ hpart, float* __restrict__ Ppart)
{
  int g = blockIdx.x * 256 + threadIdx.x;
  int s = g & 15;
  int d = (g >> 4) & (DI - 1);
  int b = (g >> 15) & (BATCH - 1);
  int c = g >> 16;

  float A_s = -expf(A_log[(size_t)d * DSTATE + s]);
  size_t row0 = (size_t)b * SEQ + c * CHT;
  const float* pD = delta  + row0 * DI + d;
  const float* pS = spikes + row0 * DI + d;
  const float* pB = bc     + row0 * NP + s;

  float h = 0.0f, P = 1.0f;
  for (int t = 0; t < CHT; ++t) {
    float dl = *pD;
    float sp = *pS, Bp = *pB;
    float a = expf(dl * A_s);
    h = fmaf(a, h, (dl * sp) * Bp);
    P *= a;
    pD += DI; pS += DI; pB += NP;
  }
  hpart[g] = h;
  Ppart[g] = P;
}

__global__ __launch_bounds__(256) void scan_combine(
    const float* __restrict__ hpart, const float* __restrict__ Ppart,
    float* __restrict__ init)
{
  int q = blockIdx.x * 256 + threadIdx.x;   // [0, CSZ)
  float H = 0.0f;
  #pragma unroll
  for (int c = 0; c < NCH; ++c) {
    init[c * CSZ + q] = H;
    H = fmaf(Ppart[c * CSZ + q], H, hpart[c * CSZ + q]);
  }
}

__global__ __launch_bounds__(256) void scan_pass2(
    const float* __restrict__ delta, const float* __restrict__ spikes,
    const float* __restrict__ bc, const float* __restrict__ xr,
    const float* __restrict__ A_log, const float* __restrict__ D_param,
    const float* __restrict__ init, float* __restrict__ yout)
{
  int g = blockIdx.x * 256 + threadIdx.x;
  int s = g & 15;
  int d = (g >> 4) & (DI - 1);
  int b = (g >> 15) & (BATCH - 1);
  int c = g >> 16;

  float A_s = -expf(A_log[(size_t)d * DSTATE + s]);
  float Dp  = D_param[d];
  size_t row0 = (size_t)b * SEQ + c * CHT;
  const float* pD = delta  + row0 * DI + d;
  const float* pS = spikes + row0 * DI + d;
  const float* pB = bc     + row0 * NP + s;
  const float* pC = pB + DSTATE;
  const float* pR = xr     + row0 * (2 * DI) + DI + d;
  float*       pY = yout   + row0 * NP + d;

  float h = init[g];
  for (int t = 0; t < CHT; ++t) {
    float dl = *pD;
    float sp = *pS, Bp = *pB, Cp = *pC;
    float a = expf(dl * A_s);
    h = fmaf(a, h, (dl * sp) * Bp);
    float v = h * Cp;
    v += __shfl_xor(v, 1, 16);
    v += __shfl_xor(v, 2, 16);
    v += __shfl_xor(v, 4, 16);
    v += __shfl_xor(v, 8, 16);
    if (s == 0) {
      float r   = *pR;
      float sig = 1.0f / (1.0f + expf(-r));
      *pY = (v + sp * Dp) * (r * sig);
    }
    pD += DI; pS += DI; pB += NP; pC += NP; pR += 2 * DI; pY += NP;
  }
}

// ---------------------------------------------------------------------------
// Row LayerNorm + final spike. o = o0 + o1 (G4's two K-partials; bias in o0),
// plus residual x.
// ---------------------------------------------------------------------------
__global__ __launch_bounds__(256) void ln_spike_kernel(
    const float* __restrict__ o0, const float* __restrict__ o1,
    const float* __restrict__ x,
    const float* __restrict__ gamma, const float* __restrict__ beta,
    float* __restrict__ out)
{
  const int row = blockIdx.x;
  const int tid = threadIdx.x;
  const float* o0row = o0 + (size_t)row * DM;
  const float* o1row = o1 + (size_t)row * DM;
  const float* xrow  = x  + (size_t)row * DM;

  float vals[4];
  float sum = 0.0f;
  #pragma unroll
  for (int j = 0; j < 4; ++j) {
    int c = tid + 256 * j;
    vals[j] = o0row[c] + o1row[c] + xrow[c];
    sum += vals[j];
  }
  #pragma unroll
  for (int off = 1; off < 64; off <<= 1) sum += __shfl_xor(sum, off, 64);

  __shared__ float ws4[4];
  const int wid = tid >> 6, lane = tid & 63;
  if (lane == 0) ws4[wid] = sum;
  __syncthreads();
  float mu = (ws4[0] + ws4[1] + ws4[2] + ws4[3]) * (1.0f / DM);

  float vs = 0.0f;
  #pragma unroll
  for (int j = 0; j < 4; ++j) { float dv = vals[j] - mu; vs += dv * dv; }
  #pragma unroll
  for (int off = 1; off < 64; off <<= 1) vs += __shfl_xor(vs, off, 64);
  __syncthreads();
  if (lane == 0) ws4[wid] = vs;
  __syncthreads();
  float var = (ws4[0] + ws4[1] + ws4[2] + ws4[3]) * (1.0f / DM);
  float inv = 1.0f / sqrtf(var + 1e-5f);

  float* outrow = out + (size_t)row * DM;
  #pragma unroll
  for (int j = 0; j < 4; ++j) {
    int c = tid + 256 * j;
    float nv = fmaf((vals[j] - mu) * inv, gamma[c], beta[c]);
    outrow[c] = (nv >= 1.0f) ? 1.0f : 0.0f;
  }
}

// ---------------------------------------------------------------------------
extern "C" void kernel_launch(void* const* d_in, const int* in_sizes, int n_in,
                              void* d_out, int out_size, void* d_ws, size_t ws_size,
                              hipStream_t stream) {
  const float* x      = (const float*)d_in[0];
  const float* W_in   = (const float*)d_in[1];
  const float* b_in   = (const float*)d_in[2];
  const float* W_conv = (const float*)d_in[3];
  const float* b_conv = (const float*)d_in[4];
  const float* W_x    = (const float*)d_in[5];
  const float* b_x    = (const float*)d_in[6];
  const float* W_dt   = (const float*)d_in[7];
  const float* b_dt   = (const float*)d_in[8];
  const float* A_log  = (const float*)d_in[9];
  const float* D_par  = (const float*)d_in[10];
  const float* W_out  = (const float*)d_in[11];
  const float* b_out  = (const float*)d_in[12];
  const float* gamma  = (const float*)d_in[13];
  const float* beta   = (const float*)d_in[14];
  float* out = (float*)d_out;

  // workspace layout (floats) — identical footprint to the proven round-2 one
  float* ws     = (float*)d_ws;
  float* xr     = ws;                                  // [ROWS, 2*DI]
  float* spikes = xr     + (size_t)ROWS * (2 * DI);    // [ROWS, DI]
  float* params = spikes + (size_t)ROWS * DI;          // [ROWS, NP]
  float* delta  = params + (size_t)ROWS * NP;          // [ROWS, DI] (softplus'd)
  float* hpart  = delta  + (size_t)ROWS * DI;          // [NCH*CSZ]
  float* Ppart  = hpart  + (size_t)NCH * CSZ;          // [NCH*CSZ]
  float* init   = Ppart  + (size_t)NCH * CSZ;          // [NCH*CSZ]
  float* o0     = xr;                                  // xr dead after scan_pass2
  float* o1     = xr + (size_t)ROWS * DM;

  dim3 blk(512);

  // G1: xr = x @ W_in + b_in          [2048 x 4096, K=1024], 512 blocks x 8 waves
  gemm_f32_kernel<0><<<dim3(32, 16, 1), blk, 0, stream>>>(
      x, DM, W_in, 2 * DI, b_in, xr, 2 * DI, 2 * DI, DM, 0LL);

  // conv + spike
  conv_spike_kernel<<<(ROWS * DI) / 256, dim3(256), 0, stream>>>(xr, W_conv, b_conv, spikes);

  // G2: params = spikes @ W_x + b_x   [2048 x 2080, K=2048], 272 blocks x 8 waves
  gemm_f32_kernel<0><<<dim3(17, 16, 1), blk, 0, stream>>>(
      spikes, DI, W_x, NP, b_x, params, NP, NP, DI, 0LL);

  // G3: delta = softplus(params[:, :DI] @ W_dt + b_dt)  [2048 x 2048, K=2048]
  gemm_f32_kernel<1><<<dim3(16, 16, 1), blk, 0, stream>>>(
      params, NP, W_dt, DI, b_dt, delta, DI, DI, DI, 0LL);

  // chunked selective scan (+ D skip + SiLU gate); y into params cols [0,DI)
  scan_pass1<<<(NCH * CSZ) / 256, dim3(256), 0, stream>>>(
      delta, spikes, params + DI, A_log, hpart, Ppart);
  scan_combine<<<CSZ / 256, dim3(256), 0, stream>>>(hpart, Ppart, init);
  scan_pass2<<<(NCH * CSZ) / 256, dim3(256), 0, stream>>>(
      delta, spikes, params + DI, xr, A_log, D_par, init, params);

  // G4: o0/o1 = y @ W_out K-halves (+b_out in o0)  [2048 x 1024, K=2x1024],
  //     256 blocks x 8 waves; partials alias xr (dead after pass2)
  gemm_f32_kernel<0><<<dim3(8, 16, 2), blk, 0, stream>>>(
      params, NP, W_out, DM, b_out, o0, DM, DM, 1024, (long long)ROWS * DM);

  // LayerNorm(o0+o1+x) + spike -> out
  ln_spike_kernel<<<ROWS, dim3(256), 0, stream>>>(o0, o1, x, gamma, beta, out);
}

// Round 8
// 1154.128 us; speedup vs baseline: 1.7625x; 1.3720x over previous
//
#include <hip/hip_runtime.h>
#include <hip/hip_bf16.h>

#define BATCH 2
#define SEQ 1024
#define DM 1024
#define DI 2048
#define DSTATE 16
#define NP (DI + 2*DSTATE)    /* 2080 */
#define ROWS (BATCH*SEQ)      /* 2048 */
#define NCH 16
#define CHT (SEQ/NCH)
#define CSZ (BATCH*DI*DSTATE) /* 65536 */

typedef short bf16x8 __attribute__((ext_vector_type(8)));
typedef float f32x4  __attribute__((ext_vector_type(4)));

__device__ __forceinline__ float softplus_f(float x){
  return fmaxf(x, 0.0f) + log1pf(expf(-fabsf(x)));
}
__device__ __forceinline__ short bf16_of(float x){
  __hip_bfloat16 h = __float2bfloat16(x);
  return *reinterpret_cast<short*>(&h);
}
__device__ __forceinline__ float f_of_bf16(short s){
  __hip_bfloat16 h = *reinterpret_cast<__hip_bfloat16*>(&s);
  return __bfloat162float(h);
}

// ---------------------------------------------------------------------------
// f32 GEMM (round-2 proven structure): 128x128 tile, BK=16, 256 thr, 8x8/thr,
// register prefetch, 2 barriers/tile. Optional 2-way inter-block split-K via
// blockIdx.z (partials to C + z*pstride, bias added by z==0 only).
// ACT: 0 none, 1 softplus.
// ---------------------------------------------------------------------------
template<int ACT>
__global__ __launch_bounds__(256, 2) void gemm_f32_kernel(
    const float* __restrict__ A, int lda,
    const float* __restrict__ B, int ldb,
    const float* __restrict__ bias,
    float* __restrict__ C, int ldc,
    int N, int kseg, long long pstride)
{
  constexpr int BM = 128, BN = 128, BK = 16;
  __shared__ float As[BK][BM + 4];
  __shared__ float Bs[BK][BN + 4];

  const int t  = threadIdx.x;
  const int bm = blockIdx.y * BM;
  const int bn = blockIdx.x * BN;
  const int kid = blockIdx.z;
  const int kbase = kid * kseg;
  const int tm = (t >> 4) << 3;
  const int tn = (t & 15) << 3;

  C += (long long)kid * pstride;

  float4 va[2], vb[2];

  auto LOAD = [&](int k0) {
    #pragma unroll
    for (int j = 0; j < 2; ++j) {
      int f  = t + 256 * j;
      int m  = f >> 2;
      int k4 = (f & 3) << 2;
      va[j] = *reinterpret_cast<const float4*>(A + (size_t)(bm + m) * lda + (k0 + k4));
      int kk = f >> 5;
      int n4 = (f & 31) << 2;
      int ncol = bn + n4;
      if (ncol < N)
        vb[j] = *reinterpret_cast<const float4*>(B + (size_t)(k0 + kk) * ldb + ncol);
      else
        vb[j] = make_float4(0.f, 0.f, 0.f, 0.f);
    }
  };
  auto STORE = [&]() {
    #pragma unroll
    for (int j = 0; j < 2; ++j) {
      int f  = t + 256 * j;
      int m  = f >> 2;
      int k4 = (f & 3) << 2;
      As[k4 + 0][m] = va[j].x;
      As[k4 + 1][m] = va[j].y;
      As[k4 + 2][m] = va[j].z;
      As[k4 + 3][m] = va[j].w;
      int kk = f >> 5;
      int n4 = (f & 31) << 2;
      *reinterpret_cast<float4*>(&Bs[kk][n4]) = vb[j];
    }
  };

  float acc[8][8];
  #pragma unroll
  for (int i = 0; i < 8; ++i)
    #pragma unroll
    for (int j = 0; j < 8; ++j) acc[i][j] = 0.0f;

  LOAD(kbase); STORE(); __syncthreads();

  const int NT = kseg >> 4;
  for (int it = 0;;) {
    const bool more = (it + 1) < NT;
    if (more) LOAD(kbase + ((it + 1) << 4));

    #pragma unroll
    for (int kk = 0; kk < BK; ++kk) {
      float a[8], b[8];
      *reinterpret_cast<float4*>(&a[0]) = *reinterpret_cast<const float4*>(&As[kk][tm]);
      *reinterpret_cast<float4*>(&a[4]) = *reinterpret_cast<const float4*>(&As[kk][tm + 4]);
      *reinterpret_cast<float4*>(&b[0]) = *reinterpret_cast<const float4*>(&Bs[kk][tn]);
      *reinterpret_cast<float4*>(&b[4]) = *reinterpret_cast<const float4*>(&Bs[kk][tn + 4]);
      #pragma unroll
      for (int i = 0; i < 8; ++i)
        #pragma unroll
        for (int j = 0; j < 8; ++j)
          acc[i][j] = fmaf(a[i], b[j], acc[i][j]);
    }
    if (!more) break;
    __syncthreads();
    STORE();
    __syncthreads();
    ++it;
  }

  const bool addb = (kid == 0);
  #pragma unroll
  for (int i = 0; i < 8; ++i) {
    float* crow = C + (size_t)(bm + tm + i) * ldc;
    #pragma unroll
    for (int j0 = 0; j0 < 8; j0 += 4) {
      int c = bn + tn + j0;
      if (c < N) {
        float4 v = make_float4(acc[i][j0], acc[i][j0+1], acc[i][j0+2], acc[i][j0+3]);
        if (addb) {
          float4 bv = *reinterpret_cast<const float4*>(bias + c);
          v.x += bv.x; v.y += bv.y; v.z += bv.z; v.w += bv.w;
        }
        if (ACT == 1) {
          v.x = softplus_f(v.x); v.y = softplus_f(v.y);
          v.z = softplus_f(v.z); v.w = softplus_f(v.w);
        }
        *reinterpret_cast<float4*>(crow + c) = v;
      }
    }
  }
}

// ---------------------------------------------------------------------------
// Convert B [K][N] f32 into 3 bf16 planes (hi/mid/lo), MFMA-tiled:
// plane[(nt*KT+kt)*512 + lane*8 + j] = B[kt*32 + 8*(lane>>4)+j][nt*16 + (lane&15)]
// ---------------------------------------------------------------------------
__global__ __launch_bounds__(256) void convB3(
    const float* __restrict__ B, int K, int N, int NT,
    short* __restrict__ P0, short* __restrict__ P1, short* __restrict__ P2)
{
  int gid  = blockIdx.x * 256 + threadIdx.x;
  int lane = gid & 63;
  int tile = gid >> 6;
  int KT   = K >> 5;
  if (tile >= NT * KT) return;
  int nt = tile / KT, kt = tile - nt * KT;
  int col  = nt * 16 + (lane & 15);
  int krow = kt * 32 + ((lane >> 4) << 3);
  bf16x8 vh, vm, vl;
  #pragma unroll
  for (int j = 0; j < 8; ++j){
    float x = (col < N) ? B[(size_t)(krow + j) * N + col] : 0.0f;
    short h = bf16_of(x);   float fh = f_of_bf16(h);
    float r = x - fh;
    short m = bf16_of(r);   float fm = f_of_bf16(m);
    short l = bf16_of(r - fm);
    vh[j] = h; vm[j] = m; vl[j] = l;
  }
  size_t o = ((size_t)tile * 64 + lane) * 8;
  *reinterpret_cast<bf16x8*>(P0 + o) = vh;
  *reinterpret_cast<bf16x8*>(P1 + o) = vm;
  *reinterpret_cast<bf16x8*>(P2 + o) = vl;
}

// ---------------------------------------------------------------------------
// MFMA GEMM for G2 only: A = pre-tiled EXACT bf16 plane (spikes), B = 3 planes.
// 128x128 tile, 256 thr (4 waves 2x2), BK=32 (one 16x16x32 step per plane).
// C = spikes @ (B0+B1+B2) + bias. N guarded.
// ---------------------------------------------------------------------------
__global__ __launch_bounds__(256, 2) void gemm_mfma_g2(
    const short* __restrict__ A0,
    const short* __restrict__ B0, const short* __restrict__ B1, const short* __restrict__ B2,
    const float* __restrict__ bias, float* __restrict__ C, int ldc,
    int N, int KT)
{
  __shared__ short lds[4 * 8 * 512];   // 32 KB: A + 3 B planes, 8 subtiles each
  const int t = threadIdx.x, lane = t & 63, w = t >> 6;
  const int wr = w >> 1, wc = w & 1;
  const int bm = blockIdx.y * 128, bn = blockIdx.x * 128;

  const short* bps[3] = {B0, B1, B2};

  f32x4 acc[4][4];
  #pragma unroll
  for (int i = 0; i < 4; ++i)
    #pragma unroll
    for (int j = 0; j < 4; ++j)
      acc[i][j] = (f32x4){0.f, 0.f, 0.f, 0.f};

  for (int kt = 0; kt < KT; ++kt){
    __syncthreads();
    for (int tau = w; tau < 32; tau += 4){
      int p = tau >> 3, sub = tau & 7;
      const short* src = (p == 0)
        ? A0         + ((size_t)((bm >> 4) + sub) * KT + kt) * 512
        : bps[p - 1] + ((size_t)((bn >> 4) + sub) * KT + kt) * 512;
      *reinterpret_cast<uint4*>(&lds[tau * 512 + lane * 8]) =
          *reinterpret_cast<const uint4*>(src + lane * 8);
    }
    __syncthreads();

    bf16x8 af[4];
    #pragma unroll
    for (int i = 0; i < 4; ++i)
      af[i] = *reinterpret_cast<const bf16x8*>(
          &lds[(wr * 4 + i) * 512 + lane * 8]);

    #pragma unroll
    for (int q = 0; q < 3; ++q){
      #pragma unroll
      for (int j = 0; j < 4; ++j){
        bf16x8 bf = *reinterpret_cast<const bf16x8*>(
            &lds[((1 + q) * 8 + wc * 4 + j) * 512 + lane * 8]);
        #pragma unroll
        for (int i = 0; i < 4; ++i)
          acc[i][j] = __builtin_amdgcn_mfma_f32_16x16x32_bf16(
              af[i], bf, acc[i][j], 0, 0, 0);
      }
    }
  }

  // C/D layout: col=lane&15, row=(lane>>4)*4+reg  [m89-verified]
  #pragma unroll
  for (int i = 0; i < 4; ++i){
    #pragma unroll
    for (int j = 0; j < 4; ++j){
      int cg = bn + (wc * 4 + j) * 16 + (lane & 15);
      if (cg >= N) continue;
      int r0 = bm + (wr * 4 + i) * 16 + ((lane >> 4) << 2);
      float bv = bias[cg];
      #pragma unroll
      for (int r = 0; r < 4; ++r)
        C[(size_t)(r0 + r) * ldc + cg] = acc[i][j][r] + bv;
    }
  }
}

// ---------------------------------------------------------------------------
// Causal depthwise conv (D_CONV=4) + heaviside spike.
// Writes f32 spikes (scan) and bf16 MFMA-tiled spikes (G2, exact {0,1}).
// ---------------------------------------------------------------------------
__global__ __launch_bounds__(256) void conv_spike_kernel(
    const float* __restrict__ xr, const float* __restrict__ W_conv,
    const float* __restrict__ b_conv, float* __restrict__ spikes,
    short* __restrict__ spikes_t)
{
  int g   = blockIdx.x * 256 + threadIdx.x;
  int c   = g & (DI - 1);
  int row = g >> 11;
  int t   = row & (SEQ - 1);

  float4 wc = reinterpret_cast<const float4*>(W_conv)[c];
  float w[4] = { wc.x, wc.y, wc.z, wc.w };
  float v = b_conv[c];
  #pragma unroll
  for (int k = 0; k < 4; ++k) {
    int tt = t - 3 + k;
    if (tt >= 0) {
      float xv = xr[(size_t)(row - 3 + k) * (2 * DI) + c];
      v = fmaf(xv, w[k], v);
    }
  }
  float sp = (v >= 1.0f) ? 1.0f : 0.0f;
  spikes[(size_t)row * DI + c] = sp;
  // A-plane tiling: plane[(mt*KT+kt)*512 + lane*8 + j],
  // row = mt*16 + (lane&15), k = kt*32 + 8*(lane>>4) + j; KT = DI/32 = 64
  int mt = row >> 4, lr = row & 15, kt = c >> 5, gg = (c & 31) >> 3, j = c & 7;
  spikes_t[((size_t)(mt * (DI/32) + kt) * 64 + lr + (gg << 4)) * 8 + j] =
      (sp != 0.0f) ? (short)0x3F80 : (short)0;
}

// ---------------------------------------------------------------------------
// Chunked selective scan (delta already softplus'd by G3 epilogue).
// ---------------------------------------------------------------------------
__global__ __launch_bounds__(256) void scan_pass1(
    const float* __restrict__ delta, const float* __restrict__ spikes,
    const float* __restrict__ bc, const float* __restrict__ A_log,
    float* __restrict__ hpart, float* __restrict__ Ppart)
{
  int g = blockIdx.x * 256 + threadIdx.x;
  int s = g & 15;
  int d = (g >> 4) & (DI - 1);
  int b = (g >> 15) & (BATCH - 1);
  int c = g >> 16;

  float A_s = -expf(A_log[(size_t)d * DSTATE + s]);
  size_t row0 = (size_t)b * SEQ + c * CHT;
  const float* pD = delta  + row0 * DI + d;
  const float* pS = spikes + row0 * DI + d;
  const float* pB = bc     + row0 * NP + s;

  float h = 0.0f, P = 1.0f;
  for (int t = 0; t < CHT; ++t) {
    float dl = *pD, sp = *pS, Bp = *pB;
    float a = expf(dl * A_s);
    h = fmaf(a, h, (dl * sp) * Bp);
    P *= a;
    pD += DI; pS += DI; pB += NP;
  }
  hpart[g] = h;
  Ppart[g] = P;
}

__global__ __launch_bounds__(256) void scan_combine(
    const float* __restrict__ hpart, const float* __restrict__ Ppart,
    float* __restrict__ init)
{
  int q = blockIdx.x * 256 + threadIdx.x;
  float H = 0.0f;
  #pragma unroll
  for (int c = 0; c < NCH; ++c) {
    init[c * CSZ + q] = H;
    H = fmaf(Ppart[c * CSZ + q], H, hpart[c * CSZ + q]);
  }
}

__global__ __launch_bounds__(256) void scan_pass2(
    const float* __restrict__ delta, const float* __restrict__ spikes,
    const float* __restrict__ bc, const float* __restrict__ xr,
    const float* __restrict__ A_log, const float* __restrict__ D_param,
    const float* __restrict__ init, float* __restrict__ yout)
{
  int g = blockIdx.x * 256 + threadIdx.x;
  int s = g & 15;
  int d = (g >> 4) & (DI - 1);
  int b = (g >> 15) & (BATCH - 1);
  int c = g >> 16;

  float A_s = -expf(A_log[(size_t)d * DSTATE + s]);
  float Dp  = D_param[d];
  size_t row0 = (size_t)b * SEQ + c * CHT;
  const float* pD = delta  + row0 * DI + d;
  const float* pS = spikes + row0 * DI + d;
  const float* pB = bc     + row0 * NP + s;
  const float* pC = pB + DSTATE;
  const float* pR = xr     + row0 * (2 * DI) + DI + d;
  float*       pY = yout   + row0 * NP + d;

  float h = init[g];
  for (int t = 0; t < CHT; ++t) {
    float dl = *pD, sp = *pS, Bp = *pB, Cp = *pC;
    float a = expf(dl * A_s);
    h = fmaf(a, h, (dl * sp) * Bp);
    float v = h * Cp;
    v += __shfl_xor(v, 1, 16);
    v += __shfl_xor(v, 2, 16);
    v += __shfl_xor(v, 4, 16);
    v += __shfl_xor(v, 8, 16);
    if (s == 0) {
      float r   = *pR;
      float sig = 1.0f / (1.0f + expf(-r));
      *pY = (v + sp * Dp) * (r * sig);
    }
    pD += DI; pS += DI; pB += NP; pC += NP; pR += 2 * DI; pY += NP;
  }
}

// ---------------------------------------------------------------------------
// Row LayerNorm + final spike. o = o0 + o1 (G4 K-partials; bias in o0) + x.
// ---------------------------------------------------------------------------
__global__ __launch_bounds__(256) void ln_spike_kernel(
    const float* __restrict__ o0, const float* __restrict__ o1,
    const float* __restrict__ x,
    const float* __restrict__ gamma, const float* __restrict__ beta,
    float* __restrict__ out)
{
  const int row = blockIdx.x;
  const int tid = threadIdx.x;
  const float* o0row = o0 + (size_t)row * DM;
  const float* o1row = o1 + (size_t)row * DM;
  const float* xrow  = x  + (size_t)row * DM;

  float vals[4];
  float sum = 0.0f;
  #pragma unroll
  for (int j = 0; j < 4; ++j) {
    int c = tid + 256 * j;
    vals[j] = o0row[c] + o1row[c] + xrow[c];
    sum += vals[j];
  }
  #pragma unroll
  for (int off = 1; off < 64; off <<= 1) sum += __shfl_xor(sum, off, 64);

  __shared__ float ws4[4];
  const int wid = tid >> 6, lane = tid & 63;
  if (lane == 0) ws4[wid] = sum;
  __syncthreads();
  float mu = (ws4[0] + ws4[1] + ws4[2] + ws4[3]) * (1.0f / DM);

  float vs = 0.0f;
  #pragma unroll
  for (int j = 0; j < 4; ++j) { float dv = vals[j] - mu; vs += dv * dv; }
  #pragma unroll
  for (int off = 1; off < 64; off <<= 1) vs += __shfl_xor(vs, off, 64);
  __syncthreads();
  if (lane == 0) ws4[wid] = vs;
  __syncthreads();
  float var = (ws4[0] + ws4[1] + ws4[2] + ws4[3]) * (1.0f / DM);
  float inv = 1.0f / sqrtf(var + 1e-5f);

  float* outrow = out + (size_t)row * DM;
  #pragma unroll
  for (int j = 0; j < 4; ++j) {
    int c = tid + 256 * j;
    float nv = fmaf((vals[j] - mu) * inv, gamma[c], beta[c]);
    outrow[c] = (nv >= 1.0f) ? 1.0f : 0.0f;
  }
}

// ---------------------------------------------------------------------------
extern "C" void kernel_launch(void* const* d_in, const int* in_sizes, int n_in,
                              void* d_out, int out_size, void* d_ws, size_t ws_size,
                              hipStream_t stream) {
  const float* x      = (const float*)d_in[0];
  const float* W_in   = (const float*)d_in[1];
  const float* b_in   = (const float*)d_in[2];
  const float* W_conv = (const float*)d_in[3];
  const float* b_conv = (const float*)d_in[4];
  const float* W_x    = (const float*)d_in[5];
  const float* b_x    = (const float*)d_in[6];
  const float* W_dt   = (const float*)d_in[7];
  const float* b_dt   = (const float*)d_in[8];
  const float* A_log  = (const float*)d_in[9];
  const float* D_par  = (const float*)d_in[10];
  const float* W_out  = (const float*)d_in[11];
  const float* b_out  = (const float*)d_in[12];
  const float* gamma  = (const float*)d_in[13];
  const float* beta   = (const float*)d_in[14];
  float* out = (float*)d_out;

  // workspace carving (round-2 proven layout + Wx planes appended)
  float* ws     = (float*)d_ws;
  float* xr     = ws;                                  // [2048][4096]
  float* spikes = xr     + (size_t)ROWS * (2 * DI);    // [2048][2048]
  float* params = spikes + (size_t)ROWS * DI;          // [2048][2080]
  float* delta  = params + (size_t)ROWS * NP;          // [2048][2048]
  float* hpart  = delta  + (size_t)ROWS * DI;
  float* Ppart  = hpart  + (size_t)NCH * CSZ;
  float* init   = Ppart  + (size_t)NCH * CSZ;
  short* Wx3    = (short*)(init + (size_t)NCH * CSZ);  // 3 x PWx shorts
  const size_t PWx = (size_t)2048 * 2176;

  short* spt = (short*)delta;   // spikes bf16-tiled: lives conv->G2; delta
                                // (f32) is first written at G3 (after G2)
  float* o0  = xr;              // xr dead after scan_pass2
  float* o1  = xr + (size_t)ROWS * DM;

  dim3 blk(256);

  // W_x -> 3 bf16 planes (hi/mid/lo), MFMA-tiled. tiles = 136*64
  convB3<<<(136 * 64 * 64) / 256, blk, 0, stream>>>(
      W_x, 2048, NP, 136, Wx3, Wx3 + PWx, Wx3 + 2 * PWx);

  // G1: xr = x @ W_in + b_in          [2048 x 4096, K=1024]
  gemm_f32_kernel<0><<<dim3(32, 16, 1), blk, 0, stream>>>(
      x, DM, W_in, 2 * DI, b_in, xr, 2 * DI, 2 * DI, DM, 0LL);

  // conv + spike (f32 + bf16-tiled)
  conv_spike_kernel<<<(ROWS * DI) / 256, blk, 0, stream>>>(
      xr, W_conv, b_conv, spikes, spt);

  // G2 (MFMA, exact): params = spikes @ W_x + b_x   [2048 x 2080, K=2048]
  gemm_mfma_g2<<<dim3(17, 16, 1), blk, 0, stream>>>(
      spt, Wx3, Wx3 + PWx, Wx3 + 2 * PWx, b_x, params, NP, NP, 64);

  // G3: delta = softplus(params[:, :DI] @ W_dt + b_dt)  [2048 x 2048, K=2048]
  gemm_f32_kernel<1><<<dim3(16, 16, 1), blk, 0, stream>>>(
      params, NP, W_dt, DI, b_dt, delta, DI, DI, DI, 0LL);

  // chunked selective scan; y -> params[:, :DI]
  scan_pass1<<<(NCH * CSZ) / 256, blk, 0, stream>>>(
      delta, spikes, params + DI, A_log, hpart, Ppart);
  scan_combine<<<CSZ / 256, blk, 0, stream>>>(hpart, Ppart, init);
  scan_pass2<<<(NCH * CSZ) / 256, blk, 0, stream>>>(
      delta, spikes, params + DI, xr, A_log, D_par, init, params);

  // G4: o0/o1 = y @ W_out K-halves (+b_out in o0)  [2048 x 1024, K=2x1024]
  gemm_f32_kernel<0><<<dim3(8, 16, 2), blk, 0, stream>>>(
      params, NP, W_out, DM, b_out, o0, DM, DM, 1024, (long long)ROWS * DM);

  // LayerNorm(o0+o1+x) + spike -> out
  ln_spike_kernel<<<ROWS, blk, 0, stream>>>(o0, o1, x, gamma, beta, out);
}